// Round 11
// baseline (466.119 us; speedup 1.0000x reference)
//
#include <hip/hip_runtime.h>

#define TT 4
#define BB 2
#define CC 128
#define DD 8
#define HHH 32
#define WWW 32
#define PP (DD*HHH*WWW)        // 8192
#define TSTRIDE (BB*CC*PP)     // 2097152
#define NWIN 8
#define SSS 1024
#define NHEAD 8
#define HDIM 16
#define THETA 0.7f
#define VTH 1.0f
#define NPERC (TT*BB*PP)       // 65536
#define EPSf 1e-5f

typedef unsigned short ushortT;
typedef _Float16 half_t;
typedef _Float16 f16x8 __attribute__((ext_vector_type(8)));
typedef float    f32x16 __attribute__((ext_vector_type(16)));

// ---------------- prep_misc: wmodT fold + both 1x1 weight f16 frags ---------
// bx<64: wmodT[o][tap][ic]; bx 64..71: kw frag; bx 72..79: pw frag
__global__ __launch_bounds__(256) void prep_misc(const float* __restrict__ qw,
        const float* __restrict__ kw, const float* __restrict__ pw,
        float* __restrict__ wmodT, half_t* __restrict__ wkfrag,
        half_t* __restrict__ wpfrag) {
    int bx = blockIdx.x;
    int tid = threadIdx.x;
    if (bx < 64) {
        int oi = bx*256 + tid;
        int o  = oi >> 7;
        int ic = oi & 127;
        const float* wp = qw + (size_t)oi*27;
        float kd = 0.f;
        #pragma unroll
        for (int t=0; t<9; t++) kd += wp[t] + wp[18+t];
        #pragma unroll
        for (int t=0; t<27; t++) {
            float v = wp[t] - ((t==13) ? THETA*kd : 0.f);
            wmodT[((size_t)o*27 + t)*CC + ic] = v;
        }
    } else {
        int job = (bx - 64) >> 3;                 // 0=kw, 1=pw
        int id  = ((bx - 64) & 7)*256 + tid;      // 0..2047
        const float* W = job ? pw : kw;
        half_t* frag   = job ? wpfrag : wkfrag;
        int lane = id & 63;
        int r = id >> 6;
        int m = r & 3;
        int kb = r >> 2;
        int o   = m*32 + (lane & 31);
        int ic0 = kb*16 + (lane>>5)*8;
        size_t base = ((size_t)(kb*4+m))*2*64*8 + (size_t)lane*8;
        #pragma unroll
        for (int j=0;j<8;j++){
            float v = W[(size_t)o*CC + ic0 + j];
            half_t h = (half_t)v;
            half_t l = (half_t)(v - (float)h);
            frag[base + 0*64*8 + j] = h;
            frag[base + 1*64*8 + j] = l;
        }
    }
}

// ---------------- conv a-frag f16-split weights ------------------------------
// wfrag[kb8][tap27][m4][sp2][lane64][8]
__global__ __launch_bounds__(256) void prep_wfrag(const float* __restrict__ wmodT,
                                                  half_t* __restrict__ wfrag) {
    int id = blockIdx.x*256 + threadIdx.x;   // 55296
    if (id >= 8*27*4*64) return;
    int lane = id & 63;
    int r = id >> 6;
    int m = r & 3; r >>= 2;
    int t = r % 27;
    int kb = r / 27;
    int o   = m*32 + (lane & 31);
    int ic0 = kb*16 + (lane>>5)*8;
    size_t base = ((size_t)(id>>6))*2*64*8 + (size_t)lane*8;
    #pragma unroll
    for (int j=0;j<8;j++){
        float v = wmodT[((size_t)o*27 + t)*CC + ic0 + j];
        half_t h = (half_t)v;
        half_t l = (half_t)(v - (float)h);
        wfrag[base + 0*64*8 + j] = h;
        wfrag[base + 1*64*8 + j] = l;
    }
}

// ---------------- f16-split padded x (h/w halos only) ------------------------
// xsp[tb][sp2][icg16][d8][hp34][wt34][ic8]; hp/wt 0,33 zero halos
__global__ __launch_bounds__(256) void build_xsplit(const float* __restrict__ x,
                                                    half_t* __restrict__ xsp) {
    int id = blockIdx.x*256 + threadIdx.x;   // 8*16*8*34*34 = 1,183,744
    if (id >= 8*16*8*34*34) return;
    int wt = id % 34; int r = id/34;
    int hp = r % 34;  r /= 34;
    int dz = r % 8;   r /= 8;
    int icg = r & 15; int tb = r >> 4;
    bool inb = (hp>=1) & (hp<=32) & (wt>=1) & (wt<=32);
    half_t h8[8], l8[8];
    #pragma unroll
    for (int j=0;j<8;j++){
        float v = 0.f;
        if (inb)
            v = x[((size_t)(tb*CC + icg*8+j))*PP + (size_t)dz*1024 + (hp-1)*32 + (wt-1)];
        half_t h = (half_t)v;
        half_t l = (half_t)(v - (float)h);
        h8[j]=h; l8[j]=l;
    }
    #pragma unroll
    for (int sp=0; sp<2; sp++){
        size_t gu = (((((size_t)tb*2 + sp)*16 + icg)*8 + dz)*34 + hp)*34 + wt;
        half_t* dst = xsp + gu*8;
        const half_t* src = (sp==0)?h8:l8;
        #pragma unroll
        for (int j=0;j<8;j++) dst[j] = src[j];
    }
}

// ---------------- conv via 32x32x16 f16 MFMA: 3-term split, 2 d-tiles/wave --
__global__ __launch_bounds__(256,2) void conv_mfma2(const half_t* __restrict__ xsp,
                                                    const half_t* __restrict__ wfrag,
                                                    float* __restrict__ y0,
                                                    float* __restrict__ y1) {
    __shared__ half_t slab[3264*8];          // 52.2 KB
    int tid  = threadIdx.x;
    int wid  = tid >> 6;
    int lane = tid & 63;
    int ln   = lane & 31;
    int half_ = lane >> 5;
    int hg = blockIdx.x;                     // 0..7
    int dp = blockIdx.y;                     // 0..3
    int z  = blockIdx.z;                     // 0..15
    int tb = z >> 1, kh = z & 1;
    int H0 = hg*4, d0 = dp*2;
    float* y = kh ? y1 : y0;

    f32x16 acc[2][4];
    #pragma unroll
    for (int dt=0;dt<2;dt++)
        #pragma unroll
        for (int m=0;m<4;m++)
            #pragma unroll
            for (int i=0;i<16;i++) acc[dt][m][i] = 0.f;

    f16x8 ca[4][2];
    #pragma unroll
    for (int m=0;m<4;m++)
        #pragma unroll
        for (int sp=0;sp<2;sp++)
            ca[m][sp] = *(const f16x8*)&wfrag[((((size_t)(kh*4*27)*4 + m)*2+sp)*64 + lane)*8];

    #pragma unroll 1
    for (int kk=0; kk<4; kk++) {
        int kb = kh*4 + kk;
        __syncthreads();
        for (int u = tid; u < 3264; u += 256) {
            int sp  = u / 1632;
            int r   = u - sp*1632;
            int icg = r / 816;
            int p   = r - icg*816;
            int dz  = p / 204;
            int r3  = p - dz*204;
            int hp  = r3 / 34;
            int wt  = r3 - hp*34;
            int dd  = d0 - 1 + dz;
            ulonglong2 v; v.x = 0; v.y = 0;
            if ((unsigned)dd < 8u) {
                size_t gu = (((((size_t)tb*2 + sp)*16 + (kb*2+icg))*8 + dd)*34 + (H0+hp))*34 + wt;
                v = *(const ulonglong2*)&xsp[gu*8];
            }
            *(ulonglong2*)&slab[(size_t)u*8] = v;
        }
        __syncthreads();
        #pragma unroll 1
        for (int t=0; t<27; t++) {
            int dz=t/9; int rr=t-dz*9; int dh=rr/3; int dw=rr-dh*3;
            f16x8 cb[2][2];
            #pragma unroll
            for (int dt=0;dt<2;dt++){
                int bpos = (dt+dz)*204 + (wid+dh)*34 + ln + dw;
                #pragma unroll
                for (int sp=0;sp<2;sp++)
                    cb[dt][sp] = *(const f16x8*)&slab[(size_t)((sp*2+half_)*816 + bpos)*8];
            }
            f16x8 na[4][2];
            int nt  = (t<26)? t+1 : 0;
            int nkb = (t<26)? kb  : ((kk<3)? kb+1 : kb);
            #pragma unroll
            for (int m=0;m<4;m++)
                #pragma unroll
                for (int sp=0;sp<2;sp++)
                    na[m][sp] = *(const f16x8*)&wfrag[((((size_t)(nkb*27+nt)*4+m)*2+sp)*64 + lane)*8];
            // 3 split terms: hh, hl, lh
            #pragma unroll
            for (int dt=0;dt<2;dt++)
                #pragma unroll
                for (int m=0;m<4;m++) acc[dt][m] = __builtin_amdgcn_mfma_f32_32x32x16_f16(ca[m][0], cb[dt][0], acc[dt][m],0,0,0);
            #pragma unroll
            for (int dt=0;dt<2;dt++)
                #pragma unroll
                for (int m=0;m<4;m++) acc[dt][m] = __builtin_amdgcn_mfma_f32_32x32x16_f16(ca[m][0], cb[dt][1], acc[dt][m],0,0,0);
            #pragma unroll
            for (int dt=0;dt<2;dt++)
                #pragma unroll
                for (int m=0;m<4;m++) acc[dt][m] = __builtin_amdgcn_mfma_f32_32x32x16_f16(ca[m][1], cb[dt][0], acc[dt][m],0,0,0);
            #pragma unroll
            for (int m=0;m<4;m++)
                #pragma unroll
                for (int sp=0;sp<2;sp++) ca[m][sp] = na[m][sp];
        }
    }
    int h = H0 + wid;
    #pragma unroll
    for (int dt=0; dt<2; dt++) {
        #pragma unroll
        for (int m=0; m<4; m++) {
            #pragma unroll
            for (int reg=0; reg<16; reg++) {
                int row = (reg&3) + 8*(reg>>2) + 4*half_;
                int o = m*32 + row;
                y[((size_t)tb*CC + o)*PP + (d0+dt)*1024 + h*32 + ln] = acc[dt][m][reg];
            }
        }
    }
}

// ---------------- k-gemm via f16 MFMA, 3-term; fused conv_add epilogue ------
// NOTE: y aliases part1 (conv kh=1 partial); per-thread read-before-write, 1:1.
__global__ __launch_bounds__(256) void kgemm_mfma(const half_t* __restrict__ xsp,
                                                  const half_t* __restrict__ wk,
                                                  float* y, float* qc) {
    int tid  = threadIdx.x;
    int wid  = tid >> 6;
    int lane = tid & 63;
    int ln   = lane & 31;
    int half_ = lane >> 5;
    int hg = blockIdx.x, d = blockIdx.y, tb = blockIdx.z;
    int h = hg*4 + wid;

    f32x16 acc[4];
    #pragma unroll
    for (int m=0;m<4;m++)
        #pragma unroll
        for (int i=0;i<16;i++) acc[m][i] = 0.f;

    #pragma unroll 2
    for (int kb=0; kb<8; kb++) {
        f16x8 b[2];
        #pragma unroll
        for (int sp=0; sp<2; sp++) {
            size_t gu = (((((size_t)tb*2 + sp)*16 + (kb*2+half_))*8 + d)*34 + (h+1))*34 + (ln+1);
            b[sp] = *(const f16x8*)&xsp[gu*8];
        }
        #pragma unroll
        for (int m=0; m<4; m++) {
            const half_t* wb = wk + ((size_t)(kb*4+m))*2*64*8 + (size_t)lane*8;
            f16x8 a0 = *(const f16x8*)&wb[0*64*8];
            f16x8 a1 = *(const f16x8*)&wb[1*64*8];
            acc[m] = __builtin_amdgcn_mfma_f32_32x32x16_f16(a0, b[0], acc[m],0,0,0);
            acc[m] = __builtin_amdgcn_mfma_f32_32x32x16_f16(a0, b[1], acc[m],0,0,0);
            acc[m] = __builtin_amdgcn_mfma_f32_32x32x16_f16(a1, b[0], acc[m],0,0,0);
        }
    }
    #pragma unroll
    for (int m=0; m<4; m++) {
        #pragma unroll
        for (int reg=0; reg<16; reg++) {
            int row = (reg&3) + 8*(reg>>2) + 4*half_;
            int o = m*32 + row;
            size_t idx = ((size_t)tb*CC + o)*PP + d*1024 + h*32 + ln;
            float p1 = y[idx];               // conv part1 (pre-overwrite)
            qc[idx] = qc[idx] + p1;          // fused conv_add
            y[idx] = acc[m][reg];            // kconv result
        }
    }
}

// ---------------- p-gemm via f16 MFMA + fused BN-stat partials --------------
__global__ __launch_bounds__(256) void pgemm_mfma(const ushortT* __restrict__ spkb,
                                                  const half_t* __restrict__ wp,
                                                  float* __restrict__ y,
                                                  float* __restrict__ ppart) {
    __shared__ float ls[4][128], ls2[4][128];
    int tid  = threadIdx.x;
    int wid  = tid >> 6;
    int lane = tid & 63;
    int ln   = lane & 31;
    int half_ = lane >> 5;
    int hg = blockIdx.x, d = blockIdx.y, tb = blockIdx.z;
    int h = hg*4 + wid;
    int p = d*1024 + h*32 + ln;

    f32x16 acc[4];
    #pragma unroll
    for (int m=0;m<4;m++)
        #pragma unroll
        for (int i=0;i<16;i++) acc[m][i] = 0.f;

    #pragma unroll 2
    for (int kb=0; kb<8; kb++) {
        f16x8 b = *(const f16x8*)&spkb[(((size_t)tb*16 + (kb*2+half_))*PP + p)*8];
        #pragma unroll
        for (int m=0; m<4; m++) {
            const half_t* wb = wp + ((size_t)(kb*4+m))*2*64*8 + (size_t)lane*8;
            f16x8 a0 = *(const f16x8*)&wb[0*64*8];
            f16x8 a1 = *(const f16x8*)&wb[1*64*8];
            acc[m] = __builtin_amdgcn_mfma_f32_32x32x16_f16(a0, b, acc[m],0,0,0);
            acc[m] = __builtin_amdgcn_mfma_f32_32x32x16_f16(a1, b, acc[m],0,0,0);
        }
    }
    #pragma unroll
    for (int m=0; m<4; m++) {
        #pragma unroll
        for (int reg=0; reg<16; reg++) {
            int row = (reg&3) + 8*(reg>>2) + 4*half_;
            int o = m*32 + row;
            y[((size_t)tb*CC + o)*PP + p] = acc[m][reg];
        }
    }
    // channel partials: butterfly over 32 lanes (deterministic), per-wave LDS
    #pragma unroll
    for (int m=0; m<4; m++) {
        #pragma unroll
        for (int reg=0; reg<16; reg++) {
            float v  = acc[m][reg];
            float v2 = v*v;
            #pragma unroll
            for (int off=1; off<32; off<<=1){
                v  += __shfl_xor(v,  off, 64);
                v2 += __shfl_xor(v2, off, 64);
            }
            if (ln == 0){
                int row = (reg&3) + 8*(reg>>2) + 4*half_;
                int o = m*32 + row;
                ls[wid][o] = v; ls2[wid][o] = v2;
            }
        }
    }
    __syncthreads();
    if (tid < 128){
        float s  = ls[0][tid]+ls[1][tid]+ls[2][tid]+ls[3][tid];
        float s2 = ls2[0][tid]+ls2[1][tid]+ls2[2][tid]+ls2[3][tid];
        int blk = (tb*8 + d)*8 + hg;         // 0..511
        ppart[(size_t)blk*256 + tid]       = s;
        ppart[(size_t)blk*256 + 128 + tid] = s2;
    }
}

// ---------------- per-(src,b,win,c) sum & sumsq partials ---------------------
__global__ __launch_bounds__(128) void win_stats(const float* __restrict__ q,
        const float* __restrict__ k, const float* __restrict__ x,
        float* __restrict__ rsum, float* __restrict__ rsq) {
    int blk = blockIdx.x;
    int src = blk >> 11;
    int r   = blk & 2047;
    const float* base = (src==0) ? q : ((src==1) ? k : x);
    int c  = r & 127;
    int wi = (r >> 7) & 7;
    int b  = r >> 10;
    int wd = wi>>2, wh = (wi>>1)&1, ww = wi&1;
    int tid = threadIdx.x;
    float s=0.f, s2=0.f;
    for (int t=0;t<TT;t++){
        const float* p = base + ((size_t)(t*BB+b)*CC + c)*PP;
        for (int si=tid; si<SSS; si+=128){
            int ld = si>>8, lh=(si>>4)&15, lw=si&15;
            float v = p[((wd*4+ld)<<10) + ((wh*16+lh)<<5) + (ww*16+lw)];
            s += v; s2 += v*v;
        }
    }
    __shared__ float ls[128], ls2[128];
    ls[tid]=s; ls2[tid]=s2; __syncthreads();
    for (int off=64;off>0;off>>=1){
        if(tid<off){ ls[tid]+=ls[tid+off]; ls2[tid]+=ls2[tid+off]; }
        __syncthreads();
    }
    if (tid==0){ rsum[blk]=ls[0]; rsq[blk]=ls2[0]; }
}

// ---------------- routing + channel-stat finalize (merged) ------------------
__global__ __launch_bounds__(128) void route_topk(const float* __restrict__ rsum,
        const float* __restrict__ rsq, float* __restrict__ sums,
        const float* __restrict__ qg, const float* __restrict__ qb,
        const float* __restrict__ kg, const float* __restrict__ kb,
        int* __restrict__ idxout) {
    __shared__ float qn[16*128], kn[16*128], ar[16*8], ss[768];
    int tid = threadIdx.x;
    for (int e=tid; e<384; e+=128){
        int src = e >> 7, c = e & 127;
        float s=0.f, s2=0.f;
        for (int bw=0; bw<16; bw++){
            int idx = src*2048 + bw*128 + c;
            s  += rsum[idx];
            s2 += rsq[idx];
        }
        sums[src*256 + c]       = s;
        sums[src*256 + 128 + c] = s2;
        ss[src*256 + c]       = s;
        ss[src*256 + 128 + c] = s2;
    }
    __syncthreads();
    for (int e=tid; e<16*128; e+=128){
        int c = e&127;
        float qm = ss[c]*(1.f/NPERC);
        float qv = ss[128+c]*(1.f/NPERC) - qm*qm;
        float qr = rsqrtf(qv + EPSf);
        qn[e] = (rsum[e]*(1.f/(TT*SSS)) - qm)*qr*qg[c] + qb[c];
        float km = ss[256+c]*(1.f/NPERC);
        float kv = ss[256+128+c]*(1.f/NPERC) - km*km;
        float kr = rsqrtf(kv + EPSf);
        kn[e] = (rsum[2048+e]*(1.f/(TT*SSS)) - km)*kr*kg[c] + kb[c];
    }
    __syncthreads();
    {
        int b = tid>>6, w=(tid>>3)&7, v=tid&7;
        float s=0.f;
        for (int c=0;c<128;c++) s += qn[(b*8+w)*128+c]*kn[(b*8+v)*128+c];
        ar[(b*8+w)*8+v] = s * 0.25f;
    }
    __syncthreads();
    if (tid < 16){
        const float* row = &ar[tid*8];
        bool used[8] = {false,false,false,false,false,false,false,false};
        for (int j=0;j<4;j++){
            int best=0; float bv=-3.0e38f;
            for (int v=0; v<8; v++){
                if (!used[v] && row[v] > bv){ bv=row[v]; best=v; }
            }
            used[best]=true;
            idxout[tid*4+j]=best;
        }
    }
}

// ---------------- LIF+BN for q,k,v -> f16 spikes, c-major windowed ----------
__global__ __launch_bounds__(256) void lif_bn_win3(const float* __restrict__ qin,
        const float* __restrict__ kin, const float* __restrict__ xin,
        ushortT* __restrict__ qs, ushortT* __restrict__ ks, ushortT* __restrict__ vs,
        const float* __restrict__ stats,
        const float* __restrict__ qg, const float* __restrict__ qb,
        const float* __restrict__ kg, const float* __restrict__ kb,
        const float* __restrict__ vg, const float* __restrict__ vb) {
    int src = blockIdx.y;
    const float* in  = (src==0) ? qin : ((src==1) ? kin : xin);
    ushortT*     spk = (src==0) ? qs  : ((src==1) ? ks  : vs);
    const float* gamma = (src==0) ? qg : ((src==1) ? kg : vg);
    const float* beta  = (src==0) ? qb : ((src==1) ? kb : vb);
    int e = blockIdx.x*256 + threadIdx.x;
    if (e >= BB*CC*PP) return;
    int p = e & (PP-1);
    int c = (e >> 13) & 127;
    int b = e >> 20;
    float mean = stats[src*256 + c]*(1.f/NPERC);
    float var  = stats[src*256 + 128 + c]*(1.f/NPERC) - mean*mean;
    float sc = rsqrtf(var+EPSf)*gamma[c];
    float sh = beta[c] - mean*sc;
    int d = p>>10, h=(p>>5)&31, w=p&31;
    int wi = ((d>>2)*2 + (h>>4))*2 + (w>>4);
    int si = (((d&3)<<4) + (h&15))*16 + (w&15);
    size_t widx = ((size_t)(b*NWIN+wi)*CC + c)*SSS + si;
    float v=0.f;
    #pragma unroll
    for (int t=0;t<TT;t++){
        float xn = in[(size_t)t*TSTRIDE + e]*sc + sh;
        v = (v+xn)*0.5f;
        float s = (v>=VTH)?1.f:0.f;
        spk[(size_t)t*TSTRIDE + widx] = (v>=VTH)?(ushortT)0x3C00:(ushortT)0;
        v *= (1.f - s);
    }
}

// ---------------- window attention + output LIF -> f16 spike frags ----------
__global__ __launch_bounds__(256) void attn_lif(const half_t* __restrict__ qspk,
        const half_t* __restrict__ kspk, const half_t* __restrict__ vspk,
        const int* __restrict__ idx, ushortT* __restrict__ spkb) {
    int id = blockIdx.x*256 + threadIdx.x;   // B*W*H*S = 131072
    if (id >= BB*NWIN*NHEAD*SSS) return;
    int s  = id & 1023;
    int hh = (id>>10) & 7;
    int wi = (id>>13) & 7;
    int b  = id>>16;
    int bw = b*NWIN+wi;
    size_t qbase = ((size_t)bw*CC + hh*HDIM)*SSS + s;
    size_t sbase[4];
    #pragma unroll
    for (int j=0;j<4;j++){
        int src = idx[bw*4+j];
        sbase[j] = ((size_t)(b*NWIN+src)*CC + hh*HDIM)*SSS + s;
    }
    int wd = wi>>2, wh = (wi>>1)&1, ww = wi&1;
    int d3 = wd*4 + (s>>8), h3 = wh*16 + ((s>>4)&15), w3 = ww*16 + (s&15);
    int p  = (d3<<10) + (h3<<5) + w3;

    float v=0.f;
    float v2[16];
    #pragma unroll
    for (int dd=0; dd<16; dd++) v2[dd]=0.f;

    #pragma unroll 1
    for (int t=0;t<TT;t++){
        size_t toff = (size_t)t*TSTRIDE;
        float km[16], vm[16];
        #pragma unroll
        for (int dd=0;dd<16;dd++){ km[dd]=0.f; vm[dd]=0.f; }
        #pragma unroll
        for (int j=0;j<4;j++){
            const half_t* kp = kspk+toff+sbase[j];
            const half_t* vp = vspk+toff+sbase[j];
            #pragma unroll
            for (int dd=0; dd<16; dd++){
                km[dd] += (float)kp[(size_t)dd*SSS];
                vm[dd] += (float)vp[(size_t)dd*SSS];
            }
        }
        const half_t* qp = qspk+toff+qbase;
        float att=0.f;
        #pragma unroll
        for (int dd=0;dd<16;dd++) att += (float)qp[(size_t)dd*SSS]*km[dd];
        att *= 0.25f;
        v = (v+att)*0.5f;
        float sp = (v>=VTH)?1.f:0.f;
        v *= (1.f-sp);
        float spq = sp*0.25f;
        union { ushortT u[8]; uint4 q4; } pk0, pk1;
        #pragma unroll
        for (int dd=0;dd<16;dd++){
            float ov = spq*vm[dd];
            v2[dd] = (v2[dd]+ov)*0.5f;
            float s2 = (v2[dd]>=VTH)?1.f:0.f;
            v2[dd] *= (1.f-s2);
            ushortT bs = (s2 != 0.f) ? (ushortT)0x3C00 : (ushortT)0;   // f16 1.0
            if (dd < 8) pk0.u[dd] = bs; else pk1.u[dd-8] = bs;
        }
        int tb2 = t*BB + b;
        size_t base = (((size_t)tb2*16 + hh*2)*PP + p)*8;
        *(uint4*)&spkb[base] = pk0.q4;
        *(uint4*)&spkb[base + (size_t)PP*8] = pk1.q4;
    }
}

// ---------------- p-stats finalize: reduce 512 block-partials ---------------
__global__ __launch_bounds__(512) void pstats_fin(const float* __restrict__ ppart,
        float* __restrict__ sum, float* __restrict__ sq) {
    __shared__ float ls[4][128], ls2[4][128];
    int tid = threadIdx.x;
    int c = tid & 127, g = tid >> 7;         // g = 0..3, 128 blocks each
    float s=0.f, s2=0.f;
    #pragma unroll 8
    for (int b=0; b<128; b++){
        int blk = g*128 + b;
        s  += ppart[(size_t)blk*256 + c];
        s2 += ppart[(size_t)blk*256 + 128 + c];
    }
    ls[g][c]=s; ls2[g][c]=s2;
    __syncthreads();
    if (tid < 128){
        sum[tid] = ls[0][tid]+ls[1][tid]+ls[2][tid]+ls[3][tid];
        sq[tid]  = ls2[0][tid]+ls2[1][tid]+ls2[2][tid]+ls2[3][tid];
    }
}

// ---------------- final BN apply ---------------------------------------------
__global__ __launch_bounds__(256) void bn_apply(const float* __restrict__ xin,
        float* __restrict__ yout,
        const float* __restrict__ sum, const float* __restrict__ sq,
        const float* __restrict__ gamma, const float* __restrict__ beta) {
    size_t i = (size_t)blockIdx.x*256 + threadIdx.x;
    if (i >= (size_t)TT*BB*CC*PP) return;
    int c = (int)((i>>13)&127);
    float mean = sum[c]*(1.f/NPERC);
    float var  = sq[c]*(1.f/NPERC) - mean*mean;
    float sc = rsqrtf(var+EPSf)*gamma[c];
    float sh = beta[c] - mean*sc;
    yout[i] = xin[i]*sc + sh;
}

extern "C" void kernel_launch(void* const* d_in, const int* in_sizes, int n_in,
                              void* d_out, int out_size, void* d_ws, size_t ws_size,
                              hipStream_t stream) {
    const float* x  = (const float*)d_in[0];
    const float* qw = (const float*)d_in[1];
    const float* qg = (const float*)d_in[2];
    const float* qb = (const float*)d_in[3];
    const float* kw = (const float*)d_in[4];
    const float* kg = (const float*)d_in[5];
    const float* kb = (const float*)d_in[6];
    const float* vg = (const float*)d_in[7];
    const float* vb = (const float*)d_in[8];
    const float* pw = (const float*)d_in[9];
    const float* pg = (const float*)d_in[10];
    const float* pb = (const float*)d_in[11];
    float* out = (float*)d_out;
    float* ws  = (float*)d_ws;

    const size_t NEL = (size_t)TT*TSTRIDE;   // 8,388,608 floats
    float* qconv = ws;                       // conv part0; later pconv
    float* kconv = ws + NEL;                 // conv part1 -> kconv -> spkb
    float* wmodT = ws + 5*NEL;               // 442368 floats; later ppart
    float* stats = ws + 5*NEL + 442368;
    float *psum=stats+768, *psq=stats+896;
    float* rsum = stats + 1024;              // 6144
    float* rsq  = rsum + 6144;               // 6144
    int*   idxp = (int*)(rsq + 6144);        // 64 ints
    half_t* wkfrag = (half_t*)(stats + 16384);          // 32768 halfs (64KB)
    half_t* wpfrag = (half_t*)(stats + 16384 + 16384);  // 32768 halfs

    // lifetimes:
    //  xsp f16 (37.8MB) at 2NEL until kgemm done
    //  wfrag f16 (1.77MB) at 4NEL; dead after conv
    //  conv part1 at NEL; consumed inside kgemm epilogue (same memory as kconv)
    //  f16 spikes q/k/v at 2NEL..3.5NEL (xsp dead)
    //  spkb f16 at NEL (kconv dead after lif)
    //  ppart overlays wmodT (dead after prep_wfrag); pconv at ws[0]
    half_t* xsp    = (half_t*)(ws + 2*NEL);
    half_t* wfrag  = (half_t*)(ws + 4*NEL);
    ushortT* spkb  = (ushortT*)(ws + NEL);
    ushortT* qspkh = (ushortT*)(ws + 2*NEL);
    ushortT* kspkh = qspkh + NEL;
    ushortT* vspkh = qspkh + 2*NEL;
    float*   pconv = ws;
    float*   ppart = wmodT;

    prep_misc<<<80,256,0,stream>>>(qw, kw, pw, wmodT, wkfrag, wpfrag);
    prep_wfrag<<<216,256,0,stream>>>(wmodT, wfrag);
    build_xsplit<<<4624,256,0,stream>>>(x, xsp);
    {
        dim3 cg(8,4,16);
        conv_mfma2<<<cg,256,0,stream>>>(xsp, wfrag, qconv, kconv);
    }
    {
        dim3 gg(8,8,8);
        kgemm_mfma<<<gg,256,0,stream>>>(xsp, wkfrag, kconv, qconv);
    }
    win_stats<<<6144,128,0,stream>>>(qconv, kconv, x, rsum, rsq);
    route_topk<<<1,128,0,stream>>>(rsum, rsq, stats, qg,qb,kg,kb, idxp);
    {
        dim3 lg(8192,3);
        lif_bn_win3<<<lg,256,0,stream>>>(qconv,kconv,x, qspkh,kspkh,vspkh,
                                         stats, qg,qb,kg,kb,vg,vb);
    }
    attn_lif<<<512,256,0,stream>>>((const half_t*)qspkh,(const half_t*)kspkh,
                                   (const half_t*)vspkh, idxp, spkb);
    {
        dim3 gg(8,8,8);
        pgemm_mfma<<<gg,256,0,stream>>>(spkb, wpfrag, pconv, ppart);
    }
    pstats_fin<<<1,512,0,stream>>>(ppart, psum, psq);
    bn_apply<<<32768,256,0,stream>>>(pconv, out, psum, psq, pg, pb);
}

// Round 12
// 409.604 us; speedup vs baseline: 1.1380x; 1.1380x over previous
//
#include <hip/hip_runtime.h>

#define TT 4
#define BB 2
#define CC 128
#define DD 8
#define HHH 32
#define WWW 32
#define PP (DD*HHH*WWW)        // 8192
#define TSTRIDE (BB*CC*PP)     // 2097152
#define NWIN 8
#define SSS 1024
#define NHEAD 8
#define HDIM 16
#define THETA 0.7f
#define VTH 1.0f
#define NPERC (TT*BB*PP)       // 65536
#define EPSf 1e-5f

typedef unsigned short ushortT;
typedef _Float16 half_t;
typedef _Float16 f16x8 __attribute__((ext_vector_type(8)));
typedef float    f32x16 __attribute__((ext_vector_type(16)));

// ---------------- wmodT: fold CDC into center tap, layout [o][tap][ic] ------
__global__ __launch_bounds__(256) void prep_wmodT(const float* __restrict__ qw,
                                                  float* __restrict__ wmodT) {
    int oi = blockIdx.x*256 + threadIdx.x;
    if (oi >= CC*CC) return;
    int o  = oi >> 7;
    int ic = oi & 127;
    const float* wp = qw + (size_t)oi*27;
    float kd = 0.f;
    #pragma unroll
    for (int t=0; t<9; t++) kd += wp[t] + wp[18+t];
    #pragma unroll
    for (int t=0; t<27; t++) {
        float v = wp[t] - ((t==13) ? THETA*kd : 0.f);
        wmodT[((size_t)o*27 + t)*CC + ic] = v;
    }
}

// ---------------- conv a-frag f16-split weights ------------------------------
// wfrag[kb8][tap27][m4][sp2][lane64][8]
__global__ __launch_bounds__(256) void prep_wfrag(const float* __restrict__ wmodT,
                                                  half_t* __restrict__ wfrag) {
    int id = blockIdx.x*256 + threadIdx.x;   // 55296
    if (id >= 8*27*4*64) return;
    int lane = id & 63;
    int r = id >> 6;
    int m = r & 3; r >>= 2;
    int t = r % 27;
    int kb = r / 27;
    int o   = m*32 + (lane & 31);
    int ic0 = kb*16 + (lane>>5)*8;
    size_t base = ((size_t)(id>>6))*2*64*8 + (size_t)lane*8;
    #pragma unroll
    for (int j=0;j<8;j++){
        float v = wmodT[((size_t)o*27 + t)*CC + ic0 + j];
        half_t h = (half_t)v;
        half_t l = (half_t)(v - (float)h);
        wfrag[base + 0*64*8 + j] = h;
        wfrag[base + 1*64*8 + j] = l;
    }
}

// ---------------- 1x1 weight f16 frags: frag[kb8][m4][sp2][lane64][8] -------
__global__ __launch_bounds__(256) void prep_w1frag(const float* __restrict__ W,
                                                   half_t* __restrict__ frag) {
    int id = blockIdx.x*256 + threadIdx.x;   // 2048
    if (id >= 2048) return;
    int lane = id & 63;
    int r = id >> 6;
    int m = r & 3;
    int kb = r >> 2;
    int o   = m*32 + (lane & 31);
    int ic0 = kb*16 + (lane>>5)*8;
    size_t base = ((size_t)(kb*4+m))*2*64*8 + (size_t)lane*8;
    #pragma unroll
    for (int j=0;j<8;j++){
        float v = W[(size_t)o*CC + ic0 + j];
        half_t h = (half_t)v;
        half_t l = (half_t)(v - (float)h);
        frag[base + 0*64*8 + j] = h;
        frag[base + 1*64*8 + j] = l;
    }
}

// ---------------- f16-split padded x (h/w halos only) ------------------------
// xsp[tb][sp2][icg16][d8][hp34][wt34][ic8]; hp/wt 0,33 zero halos
__global__ __launch_bounds__(256) void build_xsplit(const float* __restrict__ x,
                                                    half_t* __restrict__ xsp) {
    int id = blockIdx.x*256 + threadIdx.x;   // 8*16*8*34*34 = 1,183,744
    if (id >= 8*16*8*34*34) return;
    int wt = id % 34; int r = id/34;
    int hp = r % 34;  r /= 34;
    int dz = r % 8;   r /= 8;
    int icg = r & 15; int tb = r >> 4;
    bool inb = (hp>=1) & (hp<=32) & (wt>=1) & (wt<=32);
    half_t h8[8], l8[8];
    #pragma unroll
    for (int j=0;j<8;j++){
        float v = 0.f;
        if (inb)
            v = x[((size_t)(tb*CC + icg*8+j))*PP + (size_t)dz*1024 + (hp-1)*32 + (wt-1)];
        half_t h = (half_t)v;
        half_t l = (half_t)(v - (float)h);
        h8[j]=h; l8[j]=l;
    }
    #pragma unroll
    for (int sp=0; sp<2; sp++){
        size_t gu = (((((size_t)tb*2 + sp)*16 + icg)*8 + dz)*34 + hp)*34 + wt;
        half_t* dst = xsp + gu*8;
        const half_t* src = (sp==0)?h8:l8;
        #pragma unroll
        for (int j=0;j<8;j++) dst[j] = src[j];
    }
}

// ---------------- conv via 32x32x16 f16 MFMA: 3-term split, 2 d-tiles/wave --
// grid (hg8, dp4, tb8*kh2); block 256 = 4 waves = 4 h-rows; wave owns d0,d0+1.
__global__ __launch_bounds__(256,2) void conv_mfma2(const half_t* __restrict__ xsp,
                                                    const half_t* __restrict__ wfrag,
                                                    float* __restrict__ y0,
                                                    float* __restrict__ y1) {
    __shared__ half_t slab[3264*8];          // 52.2 KB
    int tid  = threadIdx.x;
    int wid  = tid >> 6;
    int lane = tid & 63;
    int ln   = lane & 31;
    int half_ = lane >> 5;
    int hg = blockIdx.x;                     // 0..7
    int dp = blockIdx.y;                     // 0..3
    int z  = blockIdx.z;                     // 0..15
    int tb = z >> 1, kh = z & 1;
    int H0 = hg*4, d0 = dp*2;
    float* y = kh ? y1 : y0;

    f32x16 acc[2][4];
    #pragma unroll
    for (int dt=0;dt<2;dt++)
        #pragma unroll
        for (int m=0;m<4;m++)
            #pragma unroll
            for (int i=0;i<16;i++) acc[dt][m][i] = 0.f;

    // a-frag prefetch for (kb=kh*4, t=0)
    f16x8 ca[4][2];
    #pragma unroll
    for (int m=0;m<4;m++)
        #pragma unroll
        for (int sp=0;sp<2;sp++)
            ca[m][sp] = *(const f16x8*)&wfrag[((((size_t)(kh*4*27)*4 + m)*2+sp)*64 + lane)*8];

    #pragma unroll 1
    for (int kk=0; kk<4; kk++) {
        int kb = kh*4 + kk;
        __syncthreads();
        // stage slab: [sp2][icg2][dz4][hp6][wt34] units of 16B
        for (int u = tid; u < 3264; u += 256) {
            int sp  = u / 1632;
            int r   = u - sp*1632;
            int icg = r / 816;
            int p   = r - icg*816;
            int dz  = p / 204;
            int r3  = p - dz*204;
            int hp  = r3 / 34;
            int wt  = r3 - hp*34;
            int dd  = d0 - 1 + dz;
            ulonglong2 v; v.x = 0; v.y = 0;
            if ((unsigned)dd < 8u) {
                size_t gu = (((((size_t)tb*2 + sp)*16 + (kb*2+icg))*8 + dd)*34 + (H0+hp))*34 + wt;
                v = *(const ulonglong2*)&xsp[gu*8];
            }
            *(ulonglong2*)&slab[(size_t)u*8] = v;
        }
        __syncthreads();
        #pragma unroll 1
        for (int t=0; t<27; t++) {
            int dz=t/9; int rr=t-dz*9; int dh=rr/3; int dw=rr-dh*3;
            // b-frags fresh from LDS: 2 d-tiles x 2 splits
            f16x8 cb[2][2];
            #pragma unroll
            for (int dt=0;dt<2;dt++){
                int bpos = (dt+dz)*204 + (wid+dh)*34 + ln + dw;
                #pragma unroll
                for (int sp=0;sp<2;sp++)
                    cb[dt][sp] = *(const f16x8*)&slab[(size_t)((sp*2+half_)*816 + bpos)*8];
            }
            // a-frag prefetch for next tap
            f16x8 na[4][2];
            int nt  = (t<26)? t+1 : 0;
            int nkb = (t<26)? kb  : ((kk<3)? kb+1 : kb);
            #pragma unroll
            for (int m=0;m<4;m++)
                #pragma unroll
                for (int sp=0;sp<2;sp++)
                    na[m][sp] = *(const f16x8*)&wfrag[((((size_t)(nkb*27+nt)*4+m)*2+sp)*64 + lane)*8];
            // 3 split terms: hh, hl, lh (ll ~ 2^-22, dropped)
            #pragma unroll
            for (int dt=0;dt<2;dt++)
                #pragma unroll
                for (int m=0;m<4;m++) acc[dt][m] = __builtin_amdgcn_mfma_f32_32x32x16_f16(ca[m][0], cb[dt][0], acc[dt][m],0,0,0);
            #pragma unroll
            for (int dt=0;dt<2;dt++)
                #pragma unroll
                for (int m=0;m<4;m++) acc[dt][m] = __builtin_amdgcn_mfma_f32_32x32x16_f16(ca[m][0], cb[dt][1], acc[dt][m],0,0,0);
            #pragma unroll
            for (int dt=0;dt<2;dt++)
                #pragma unroll
                for (int m=0;m<4;m++) acc[dt][m] = __builtin_amdgcn_mfma_f32_32x32x16_f16(ca[m][1], cb[dt][0], acc[dt][m],0,0,0);
            #pragma unroll
            for (int m=0;m<4;m++)
                #pragma unroll
                for (int sp=0;sp<2;sp++) ca[m][sp] = na[m][sp];
        }
    }
    int h = H0 + wid;
    #pragma unroll
    for (int dt=0; dt<2; dt++) {
        #pragma unroll
        for (int m=0; m<4; m++) {
            #pragma unroll
            for (int reg=0; reg<16; reg++) {
                int row = (reg&3) + 8*(reg>>2) + 4*half_;
                int o = m*32 + row;
                y[((size_t)tb*CC + o)*PP + (d0+dt)*1024 + h*32 + ln] = acc[dt][m][reg];
            }
        }
    }
}

// ---------------- sum the two kb-half partials -------------------------------
__global__ __launch_bounds__(256) void conv_add(float* __restrict__ q,
                                                const float* __restrict__ p1) {
    size_t i = ((size_t)blockIdx.x*256 + threadIdx.x)*4;
    float4 a = *(const float4*)&q[i];
    float4 b = *(const float4*)&p1[i];
    a.x+=b.x; a.y+=b.y; a.z+=b.z; a.w+=b.w;
    *(float4*)&q[i] = a;
}

// ---------------- k-gemm (1x1) via f16 MFMA, 3-term split, reads xsp --------
__global__ __launch_bounds__(256) void kgemm_mfma(const half_t* __restrict__ xsp,
                                                  const half_t* __restrict__ wk,
                                                  float* __restrict__ y) {
    int tid  = threadIdx.x;
    int wid  = tid >> 6;
    int lane = tid & 63;
    int ln   = lane & 31;
    int half_ = lane >> 5;
    int hg = blockIdx.x, d = blockIdx.y, tb = blockIdx.z;
    int h = hg*4 + wid;

    f32x16 acc[4];
    #pragma unroll
    for (int m=0;m<4;m++)
        #pragma unroll
        for (int i=0;i<16;i++) acc[m][i] = 0.f;

    #pragma unroll 2
    for (int kb=0; kb<8; kb++) {
        f16x8 b[2];
        #pragma unroll
        for (int sp=0; sp<2; sp++) {
            size_t gu = (((((size_t)tb*2 + sp)*16 + (kb*2+half_))*8 + d)*34 + (h+1))*34 + (ln+1);
            b[sp] = *(const f16x8*)&xsp[gu*8];
        }
        #pragma unroll
        for (int m=0; m<4; m++) {
            const half_t* wb = wk + ((size_t)(kb*4+m))*2*64*8 + (size_t)lane*8;
            f16x8 a0 = *(const f16x8*)&wb[0*64*8];
            f16x8 a1 = *(const f16x8*)&wb[1*64*8];
            acc[m] = __builtin_amdgcn_mfma_f32_32x32x16_f16(a0, b[0], acc[m],0,0,0);
            acc[m] = __builtin_amdgcn_mfma_f32_32x32x16_f16(a0, b[1], acc[m],0,0,0);
            acc[m] = __builtin_amdgcn_mfma_f32_32x32x16_f16(a1, b[0], acc[m],0,0,0);
        }
    }
    #pragma unroll
    for (int m=0; m<4; m++) {
        #pragma unroll
        for (int reg=0; reg<16; reg++) {
            int row = (reg&3) + 8*(reg>>2) + 4*half_;
            int o = m*32 + row;
            y[((size_t)tb*CC + o)*PP + d*1024 + h*32 + ln] = acc[m][reg];
        }
    }
}

// ---------------- p-gemm via f16 MFMA: exact f16 spikes x 2-split weights ---
__global__ __launch_bounds__(256) void pgemm_mfma(const ushortT* __restrict__ spkb,
                                                  const half_t* __restrict__ wp,
                                                  float* __restrict__ y) {
    int tid  = threadIdx.x;
    int wid  = tid >> 6;
    int lane = tid & 63;
    int ln   = lane & 31;
    int half_ = lane >> 5;
    int hg = blockIdx.x, d = blockIdx.y, tb = blockIdx.z;
    int h = hg*4 + wid;
    int p = d*1024 + h*32 + ln;

    f32x16 acc[4];
    #pragma unroll
    for (int m=0;m<4;m++)
        #pragma unroll
        for (int i=0;i<16;i++) acc[m][i] = 0.f;

    #pragma unroll 2
    for (int kb=0; kb<8; kb++) {
        f16x8 b = *(const f16x8*)&spkb[(((size_t)tb*16 + (kb*2+half_))*PP + p)*8];
        #pragma unroll
        for (int m=0; m<4; m++) {
            const half_t* wb = wp + ((size_t)(kb*4+m))*2*64*8 + (size_t)lane*8;
            f16x8 a0 = *(const f16x8*)&wb[0*64*8];
            f16x8 a1 = *(const f16x8*)&wb[1*64*8];
            acc[m] = __builtin_amdgcn_mfma_f32_32x32x16_f16(a0, b, acc[m],0,0,0);
            acc[m] = __builtin_amdgcn_mfma_f32_32x32x16_f16(a1, b, acc[m],0,0,0);
        }
    }
    #pragma unroll
    for (int m=0; m<4; m++) {
        #pragma unroll
        for (int reg=0; reg<16; reg++) {
            int row = (reg&3) + 8*(reg>>2) + 4*half_;
            int o = m*32 + row;
            y[((size_t)tb*CC + o)*PP + p] = acc[m][reg];
        }
    }
}

// ---------------- per-(src,b,win,c) sum & sumsq partials ---------------------
__global__ __launch_bounds__(128) void win_stats(const float* __restrict__ q,
        const float* __restrict__ k, const float* __restrict__ x,
        float* __restrict__ rsum, float* __restrict__ rsq) {
    int blk = blockIdx.x;
    int src = blk >> 11;
    int r   = blk & 2047;
    const float* base = (src==0) ? q : ((src==1) ? k : x);
    int c  = r & 127;
    int wi = (r >> 7) & 7;
    int b  = r >> 10;
    int wd = wi>>2, wh = (wi>>1)&1, ww = wi&1;
    int tid = threadIdx.x;
    float s=0.f, s2=0.f;
    for (int t=0;t<TT;t++){
        const float* p = base + ((size_t)(t*BB+b)*CC + c)*PP;
        for (int si=tid; si<SSS; si+=128){
            int ld = si>>8, lh=(si>>4)&15, lw=si&15;
            float v = p[((wd*4+ld)<<10) + ((wh*16+lh)<<5) + (ww*16+lw)];
            s += v; s2 += v*v;
        }
    }
    __shared__ float ls[128], ls2[128];
    ls[tid]=s; ls2[tid]=s2; __syncthreads();
    for (int off=64;off>0;off>>=1){
        if(tid<off){ ls[tid]+=ls[tid+off]; ls2[tid]+=ls2[tid+off]; }
        __syncthreads();
    }
    if (tid==0){ rsum[blk]=ls[0]; rsq[blk]=ls2[0]; }
}

// ---------------- finalize per-channel stats for q,k,v ----------------------
__global__ __launch_bounds__(384) void stats_fin(const float* __restrict__ rsum,
        const float* __restrict__ rsq, float* __restrict__ sums) {
    int tid = threadIdx.x;
    int src = tid >> 7, c = tid & 127;
    float s=0.f, s2=0.f;
    for (int bw=0; bw<16; bw++){
        int idx = src*2048 + bw*128 + c;
        s  += rsum[idx];
        s2 += rsq[idx];
    }
    sums[src*256 + c]       = s;
    sums[src*256 + 128 + c] = s2;
}

// ---------------- routing: normalize regions, a_r, top-4 --------------------
__global__ __launch_bounds__(128) void route_topk(const float* __restrict__ qreg,
        const float* __restrict__ kreg,
        const float* __restrict__ qsum, const float* __restrict__ qsq,
        const float* __restrict__ ksum, const float* __restrict__ ksq,
        const float* __restrict__ qg, const float* __restrict__ qb,
        const float* __restrict__ kg, const float* __restrict__ kb,
        int* __restrict__ idxout) {
    __shared__ float qn[16*128], kn[16*128], ar[16*8];
    int tid = threadIdx.x;
    for (int e=tid; e<16*128; e+=128){
        int c = e&127;
        float qm = qsum[c]*(1.f/NPERC);
        float qv = qsq[c]*(1.f/NPERC) - qm*qm;
        float qr = rsqrtf(qv + EPSf);
        qn[e] = (qreg[e]*(1.f/(TT*SSS)) - qm)*qr*qg[c] + qb[c];
        float km = ksum[c]*(1.f/NPERC);
        float kv = ksq[c]*(1.f/NPERC) - km*km;
        float kr = rsqrtf(kv + EPSf);
        kn[e] = (kreg[e]*(1.f/(TT*SSS)) - km)*kr*kg[c] + kb[c];
    }
    __syncthreads();
    {
        int b = tid>>6, w=(tid>>3)&7, v=tid&7;
        float s=0.f;
        for (int c=0;c<128;c++) s += qn[(b*8+w)*128+c]*kn[(b*8+v)*128+c];
        ar[(b*8+w)*8+v] = s * 0.25f;
    }
    __syncthreads();
    if (tid < 16){
        const float* row = &ar[tid*8];
        bool used[8] = {false,false,false,false,false,false,false,false};
        for (int j=0;j<4;j++){
            int best=0; float bv=-3.0e38f;
            for (int v=0; v<8; v++){
                if (!used[v] && row[v] > bv){ bv=row[v]; best=v; }
            }
            used[best]=true;
            idxout[tid*4+j]=best;
        }
    }
}

// ---------------- LIF+BN for q,k,v in ONE launch (grid.y = src) -------------
__global__ __launch_bounds__(256) void lif_bn_win3(const float* __restrict__ qin,
        const float* __restrict__ kin, const float* __restrict__ xin,
        float* __restrict__ qs, float* __restrict__ ks, float* __restrict__ vs,
        const float* __restrict__ stats,
        const float* __restrict__ qg, const float* __restrict__ qb,
        const float* __restrict__ kg, const float* __restrict__ kb,
        const float* __restrict__ vg, const float* __restrict__ vb) {
    int src = blockIdx.y;
    const float* in  = (src==0) ? qin : ((src==1) ? kin : xin);
    float*       spk = (src==0) ? qs  : ((src==1) ? ks  : vs);
    const float* gamma = (src==0) ? qg : ((src==1) ? kg : vg);
    const float* beta  = (src==0) ? qb : ((src==1) ? kb : vb);
    int e = blockIdx.x*256 + threadIdx.x;
    if (e >= BB*CC*PP) return;
    int p = e & (PP-1);
    int c = (e >> 13) & 127;
    int b = e >> 20;
    float mean = stats[src*256 + c]*(1.f/NPERC);
    float var  = stats[src*256 + 128 + c]*(1.f/NPERC) - mean*mean;
    float sc = rsqrtf(var+EPSf)*gamma[c];
    float sh = beta[c] - mean*sc;
    int d = p>>10, h=(p>>5)&31, w=p&31;
    int wi = ((d>>2)*2 + (h>>4))*2 + (w>>4);
    int si = (((d&3)<<4) + (h&15))*16 + (w&15);
    size_t widx = ((size_t)(b*NWIN+wi)*CC + c)*SSS + si;
    float v=0.f;
    #pragma unroll
    for (int t=0;t<TT;t++){
        float xn = in[(size_t)t*TSTRIDE + e]*sc + sh;
        v = (v+xn)*0.5f;
        float s = (v>=VTH)?1.f:0.f;
        spk[(size_t)t*TSTRIDE + widx] = s;
        v *= (1.f - s);
    }
}

// ---------------- window attention + output LIF -> f16 spike frags ----------
// spkb[tb = t*B+b][icg16][p8192][8] f16 {0,1}
__global__ __launch_bounds__(256) void attn_lif(const float* __restrict__ qspk,
        const float* __restrict__ kspk, const float* __restrict__ vspk,
        const int* __restrict__ idx, ushortT* __restrict__ spkb) {
    int id = blockIdx.x*256 + threadIdx.x;   // B*W*H*S = 131072
    if (id >= BB*NWIN*NHEAD*SSS) return;
    int s  = id & 1023;
    int hh = (id>>10) & 7;
    int wi = (id>>13) & 7;
    int b  = id>>16;
    int bw = b*NWIN+wi;
    size_t qbase = ((size_t)bw*CC + hh*HDIM)*SSS + s;
    size_t sbase[4];
    #pragma unroll
    for (int j=0;j<4;j++){
        int src = idx[bw*4+j];
        sbase[j] = ((size_t)(b*NWIN+src)*CC + hh*HDIM)*SSS + s;
    }
    int wd = wi>>2, wh = (wi>>1)&1, ww = wi&1;
    int d3 = wd*4 + (s>>8), h3 = wh*16 + ((s>>4)&15), w3 = ww*16 + (s&15);
    int p  = (d3<<10) + (h3<<5) + w3;

    float v=0.f;
    float v2[16];
    #pragma unroll
    for (int dd=0; dd<16; dd++) v2[dd]=0.f;

    #pragma unroll 1
    for (int t=0;t<TT;t++){
        size_t toff = (size_t)t*TSTRIDE;
        float km[16], vm[16];
        #pragma unroll
        for (int dd=0;dd<16;dd++){ km[dd]=0.f; vm[dd]=0.f; }
        #pragma unroll
        for (int j=0;j<4;j++){
            const float* kp = kspk+toff+sbase[j];
            const float* vp = vspk+toff+sbase[j];
            #pragma unroll
            for (int dd=0; dd<16; dd++){
                km[dd] += kp[(size_t)dd*SSS];
                vm[dd] += vp[(size_t)dd*SSS];
            }
        }
        const float* qp = qspk+toff+qbase;
        float att=0.f;
        #pragma unroll
        for (int dd=0;dd<16;dd++) att += qp[(size_t)dd*SSS]*km[dd];
        att *= 0.25f;
        v = (v+att)*0.5f;
        float sp = (v>=VTH)?1.f:0.f;
        v *= (1.f-sp);
        float spq = sp*0.25f;
        union { ushortT u[8]; uint4 q4; } pk0, pk1;
        #pragma unroll
        for (int dd=0;dd<16;dd++){
            float ov = spq*vm[dd];
            v2[dd] = (v2[dd]+ov)*0.5f;
            float s2 = (v2[dd]>=VTH)?1.f:0.f;
            v2[dd] *= (1.f-s2);
            ushortT bs = (s2 != 0.f) ? (ushortT)0x3C00 : (ushortT)0;   // f16 1.0
            if (dd < 8) pk0.u[dd] = bs; else pk1.u[dd-8] = bs;
        }
        int tb2 = t*BB + b;
        size_t base = (((size_t)tb2*16 + hh*2)*PP + p)*8;
        *(uint4*)&spkb[base] = pk0.q4;
        *(uint4*)&spkb[base + (size_t)PP*8] = pk1.q4;
    }
}

// ---------------- p-stats: partials over (tb,c), then finalize ---------------
__global__ __launch_bounds__(256) void pstats_part(const float* __restrict__ xin,
        float* __restrict__ part_sum, float* __restrict__ part_sq) {
    int blk = blockIdx.x;                    // tb*128 + c
    int c = blk & 127, tb = blk >> 7;
    int tid = threadIdx.x;
    const float* p = xin + ((size_t)tb*CC + c)*PP;
    float s=0.f, s2=0.f;
    for (int i=tid; i<PP; i+=256){ float v=p[i]; s+=v; s2+=v*v; }
    __shared__ float ls[256], ls2[256];
    ls[tid]=s; ls2[tid]=s2; __syncthreads();
    for (int off=128; off>0; off>>=1){
        if (tid<off){ ls[tid]+=ls[tid+off]; ls2[tid]+=ls2[tid+off]; }
        __syncthreads();
    }
    if (tid==0){ part_sum[blk]=ls[0]; part_sq[blk]=ls2[0]; }
}

__global__ __launch_bounds__(128) void pstats_fin(const float* __restrict__ part_sum,
        const float* __restrict__ part_sq, float* __restrict__ sum,
        float* __restrict__ sq) {
    int c = threadIdx.x;
    float s=0.f, s2=0.f;
    for (int tb=0; tb<8; tb++){
        s  += part_sum[tb*128+c];
        s2 += part_sq[tb*128+c];
    }
    sum[c]=s; sq[c]=s2;
}

// ---------------- final BN apply ---------------------------------------------
__global__ __launch_bounds__(256) void bn_apply(const float* __restrict__ xin,
        float* __restrict__ yout,
        const float* __restrict__ sum, const float* __restrict__ sq,
        const float* __restrict__ gamma, const float* __restrict__ beta) {
    size_t i = (size_t)blockIdx.x*256 + threadIdx.x;
    if (i >= (size_t)TT*BB*CC*PP) return;
    int c = (int)((i>>13)&127);
    float mean = sum[c]*(1.f/NPERC);
    float var  = sq[c]*(1.f/NPERC) - mean*mean;
    float sc = rsqrtf(var+EPSf)*gamma[c];
    float sh = beta[c] - mean*sc;
    yout[i] = xin[i]*sc + sh;
}

extern "C" void kernel_launch(void* const* d_in, const int* in_sizes, int n_in,
                              void* d_out, int out_size, void* d_ws, size_t ws_size,
                              hipStream_t stream) {
    const float* x  = (const float*)d_in[0];
    const float* qw = (const float*)d_in[1];
    const float* qg = (const float*)d_in[2];
    const float* qb = (const float*)d_in[3];
    const float* kw = (const float*)d_in[4];
    const float* kg = (const float*)d_in[5];
    const float* kb = (const float*)d_in[6];
    const float* vg = (const float*)d_in[7];
    const float* vb = (const float*)d_in[8];
    const float* pw = (const float*)d_in[9];
    const float* pg = (const float*)d_in[10];
    const float* pb = (const float*)d_in[11];
    float* out = (float*)d_out;
    float* ws  = (float*)d_ws;

    const size_t NEL = (size_t)TT*TSTRIDE;   // 8,388,608 floats
    float* qconv = ws;                       // conv part0
    float* kconv = ws + NEL;                 // conv part1, then kconv
    float* qspk  = ws + 2*NEL;
    float* kspk  = ws + 3*NEL;
    float* vspk  = ws + 4*NEL;
    float* wmodT = ws + 5*NEL;               // 442368 floats
    float* stats = ws + 5*NEL + 442368;
    float *qsum=stats,     *qsq=stats+128,  *ksum=stats+256, *ksq=stats+384,
          *psum=stats+768, *psq=stats+896;
    float* rsum = stats + 1024;              // 6144
    float* rsq  = rsum + 6144;               // 6144
    float* ppart_sum = rsq + 6144;           // 1024
    float* ppart_sq  = ppart_sum + 1024;     // 1024
    int*   idxp = (int*)(ppart_sq + 1024);   // 64 ints

    // lifetimes (S9 layout):
    //  xsp f16 (37.8MB) at 2NEL (spans into kspk region) until kgemm done
    //  wfrag/wkfrag f16 at 4NEL; dead before lif writes vspk
    //  conv part1 at NEL; conv_add consumes it BEFORE kgemm rewrites (kconv)
    //  float spikes q/k/v at 2NEL/3NEL/4NEL (xsp dead by then)
    //  spkb f16 at NEL (kconv dead after lif)
    //  wpfrag at 4NEL after attn (vspk dead); pconv at 2NEL (qspk dead)
    half_t* xsp    = (half_t*)(ws + 2*NEL);
    half_t* wfrag  = (half_t*)(ws + 4*NEL);
    half_t* wkfrag = (half_t*)(ws + 4*NEL) + 884736;
    half_t* wpfrag = (half_t*)(ws + 4*NEL);
    ushortT* spkb  = (ushortT*)(ws + NEL);
    float*   pconv = ws + 2*NEL;
    float*   part1 = kconv;

    prep_wmodT<<<64,256,0,stream>>>(qw, wmodT);
    prep_wfrag<<<216,256,0,stream>>>(wmodT, wfrag);
    prep_w1frag<<<8,256,0,stream>>>(kw, wkfrag);
    build_xsplit<<<4624,256,0,stream>>>(x, xsp);
    {
        dim3 cg(8,4,16);
        conv_mfma2<<<cg,256,0,stream>>>(xsp, wfrag, qconv, part1);
    }
    conv_add<<<8192,256,0,stream>>>(qconv, part1);
    {
        dim3 gg(8,8,8);
        kgemm_mfma<<<gg,256,0,stream>>>(xsp, wkfrag, kconv);
    }
    win_stats<<<6144,128,0,stream>>>(qconv, kconv, x, rsum, rsq);
    stats_fin<<<1,384,0,stream>>>(rsum, rsq, stats);
    route_topk<<<1,128,0,stream>>>(rsum, rsum+2048, qsum,qsq,ksum,ksq,qg,qb,kg,kb,idxp);
    {
        dim3 lg(8192,3);
        lif_bn_win3<<<lg,256,0,stream>>>(qconv,kconv,x, qspk,kspk,vspk,
                                         stats, qg,qb,kg,kb,vg,vb);
    }
    attn_lif<<<512,256,0,stream>>>(qspk,kspk,vspk,idxp,spkb);
    prep_w1frag<<<8,256,0,stream>>>(pw, wpfrag);
    {
        dim3 gg(8,8,8);
        pgemm_mfma<<<gg,256,0,stream>>>(spkb, wpfrag, pconv);
    }
    pstats_part<<<1024,256,0,stream>>>(pconv, ppart_sum, ppart_sq);
    pstats_fin<<<1,128,0,stream>>>(ppart_sum, ppart_sq, psum, psq);
    bn_apply<<<32768,256,0,stream>>>(pconv, out, psum, psq, pg, pb);
}

// Round 13
// 401.318 us; speedup vs baseline: 1.1615x; 1.0206x over previous
//
#include <hip/hip_runtime.h>

#define TT 4
#define BB 2
#define CC 128
#define DD 8
#define HHH 32
#define WWW 32
#define PP (DD*HHH*WWW)        // 8192
#define TSTRIDE (BB*CC*PP)     // 2097152
#define NWIN 8
#define SSS 1024
#define NHEAD 8
#define HDIM 16
#define THETA 0.7f
#define VTH 1.0f
#define NPERC (TT*BB*PP)       // 65536
#define EPSf 1e-5f

typedef unsigned short ushortT;
typedef _Float16 half_t;
typedef _Float16 f16x8 __attribute__((ext_vector_type(8)));
typedef float    f32x16 __attribute__((ext_vector_type(16)));

typedef const __attribute__((address_space(1))) void* as1_cvp;
typedef __attribute__((address_space(3))) void* as3_vp;

// ---------------- wmodT: fold CDC into center tap, layout [o][tap][ic] ------
__global__ __launch_bounds__(256) void prep_wmodT(const float* __restrict__ qw,
                                                  float* __restrict__ wmodT) {
    int oi = blockIdx.x*256 + threadIdx.x;
    if (oi >= CC*CC) return;
    int o  = oi >> 7;
    int ic = oi & 127;
    const float* wp = qw + (size_t)oi*27;
    float kd = 0.f;
    #pragma unroll
    for (int t=0; t<9; t++) kd += wp[t] + wp[18+t];
    #pragma unroll
    for (int t=0; t<27; t++) {
        float v = wp[t] - ((t==13) ? THETA*kd : 0.f);
        wmodT[((size_t)o*27 + t)*CC + ic] = v;
    }
}

// ---------------- conv a-frag f16-split weights ------------------------------
// wfrag[kb8][tap27][m4][sp2][lane64][8]
__global__ __launch_bounds__(256) void prep_wfrag(const float* __restrict__ wmodT,
                                                  half_t* __restrict__ wfrag) {
    int id = blockIdx.x*256 + threadIdx.x;   // 55296
    if (id >= 8*27*4*64) return;
    int lane = id & 63;
    int r = id >> 6;
    int m = r & 3; r >>= 2;
    int t = r % 27;
    int kb = r / 27;
    int o   = m*32 + (lane & 31);
    int ic0 = kb*16 + (lane>>5)*8;
    size_t base = ((size_t)(id>>6))*2*64*8 + (size_t)lane*8;
    #pragma unroll
    for (int j=0;j<8;j++){
        float v = wmodT[((size_t)o*27 + t)*CC + ic0 + j];
        half_t h = (half_t)v;
        half_t l = (half_t)(v - (float)h);
        wfrag[base + 0*64*8 + j] = h;
        wfrag[base + 1*64*8 + j] = l;
    }
}

// ---------------- 1x1 weight f16 frags: frag[kb8][m4][sp2][lane64][8] -------
__global__ __launch_bounds__(256) void prep_w1frag(const float* __restrict__ W,
                                                   half_t* __restrict__ frag) {
    int id = blockIdx.x*256 + threadIdx.x;   // 2048
    if (id >= 2048) return;
    int lane = id & 63;
    int r = id >> 6;
    int m = r & 3;
    int kb = r >> 2;
    int o   = m*32 + (lane & 31);
    int ic0 = kb*16 + (lane>>5)*8;
    size_t base = ((size_t)(kb*4+m))*2*64*8 + (size_t)lane*8;
    #pragma unroll
    for (int j=0;j<8;j++){
        float v = W[(size_t)o*CC + ic0 + j];
        half_t h = (half_t)v;
        half_t l = (half_t)(v - (float)h);
        frag[base + 0*64*8 + j] = h;
        frag[base + 1*64*8 + j] = l;
    }
}

// ---------------- f16-split padded x (h/w halos only) ------------------------
// xsp[tb][sp2][icg16][d8][hp34][wt34][ic8]; hp/wt 0,33 zero halos
__global__ __launch_bounds__(256) void build_xsplit(const float* __restrict__ x,
                                                    half_t* __restrict__ xsp) {
    int id = blockIdx.x*256 + threadIdx.x;   // 8*16*8*34*34 = 1,183,744
    if (id >= 8*16*8*34*34) return;
    int wt = id % 34; int r = id/34;
    int hp = r % 34;  r /= 34;
    int dz = r % 8;   r /= 8;
    int icg = r & 15; int tb = r >> 4;
    bool inb = (hp>=1) & (hp<=32) & (wt>=1) & (wt<=32);
    half_t h8[8], l8[8];
    #pragma unroll
    for (int j=0;j<8;j++){
        float v = 0.f;
        if (inb)
            v = x[((size_t)(tb*CC + icg*8+j))*PP + (size_t)dz*1024 + (hp-1)*32 + (wt-1)];
        half_t h = (half_t)v;
        half_t l = (half_t)(v - (float)h);
        h8[j]=h; l8[j]=l;
    }
    #pragma unroll
    for (int sp=0; sp<2; sp++){
        size_t gu = (((((size_t)tb*2 + sp)*16 + icg)*8 + dz)*34 + hp)*34 + wt;
        half_t* dst = xsp + gu*8;
        const half_t* src = (sp==0)?h8:l8;
        #pragma unroll
        for (int j=0;j<8;j++) dst[j] = src[j];
    }
}

// ---------------- conv via 32x32x16 f16 MFMA: 3-term split, 2 d-tiles/wave --
// grid (hg8, dp4, tb8*kh2); block 256 = 4 waves = 4 h-rows; wave owns d0,d0+1.
// Staging via global_load_lds width=16 (async direct-to-LDS, no VGPR hop).
__global__ __launch_bounds__(256,2) void conv_mfma2(const half_t* __restrict__ xsp,
                                                    const half_t* __restrict__ wfrag,
                                                    float* __restrict__ y0,
                                                    float* __restrict__ y1) {
    __shared__ half_t slab[3264*8];          // 52.2 KB
    int tid  = threadIdx.x;
    int wid  = tid >> 6;
    int lane = tid & 63;
    int ln   = lane & 31;
    int half_ = lane >> 5;
    int hg = blockIdx.x;                     // 0..7
    int dp = blockIdx.y;                     // 0..3
    int z  = blockIdx.z;                     // 0..15
    int tb = z >> 1, kh = z & 1;
    int H0 = hg*4, d0 = dp*2;
    float* y = kh ? y1 : y0;

    f32x16 acc[2][4];
    #pragma unroll
    for (int dt=0;dt<2;dt++)
        #pragma unroll
        for (int m=0;m<4;m++)
            #pragma unroll
            for (int i=0;i<16;i++) acc[dt][m][i] = 0.f;

    // a-frag prefetch for (kb=kh*4, t=0)
    f16x8 ca[4][2];
    #pragma unroll
    for (int m=0;m<4;m++)
        #pragma unroll
        for (int sp=0;sp<2;sp++)
            ca[m][sp] = *(const f16x8*)&wfrag[((((size_t)(kh*4*27)*4 + m)*2+sp)*64 + lane)*8];

    #pragma unroll 1
    for (int kk=0; kk<4; kk++) {
        int kb = kh*4 + kk;
        __syncthreads();
        // stage slab: [sp2][icg2][dz4][hp6][wt34] units of 16B, async to LDS
        #pragma unroll 1
        for (int u = tid; u < 3264; u += 256) {
            int sp  = u / 1632;
            int r   = u - sp*1632;
            int icg = r / 816;
            int p   = r - icg*816;
            int dz  = p / 204;
            int r3  = p - dz*204;
            int hp  = r3 / 34;
            int wt  = r3 - hp*34;
            int dd  = d0 - 1 + dz;
            half_t* ldst = &slab[(size_t)u*8];
            if ((unsigned)dd < 8u) {
                size_t gu = (((((size_t)tb*2 + sp)*16 + (kb*2+icg))*8 + dd)*34 + (H0+hp))*34 + wt;
                __builtin_amdgcn_global_load_lds((as1_cvp)&xsp[gu*8], (as3_vp)ldst, 16, 0, 0);
            } else {
                ulonglong2 zz; zz.x = 0; zz.y = 0;
                *(ulonglong2*)ldst = zz;
            }
        }
        __syncthreads();
        #pragma unroll 1
        for (int t=0; t<27; t++) {
            int dz=t/9; int rr=t-dz*9; int dh=rr/3; int dw=rr-dh*3;
            // b-frags fresh from LDS: 2 d-tiles x 2 splits
            f16x8 cb[2][2];
            #pragma unroll
            for (int dt=0;dt<2;dt++){
                int bpos = (dt+dz)*204 + (wid+dh)*34 + ln + dw;
                #pragma unroll
                for (int sp=0;sp<2;sp++)
                    cb[dt][sp] = *(const f16x8*)&slab[(size_t)((sp*2+half_)*816 + bpos)*8];
            }
            // a-frag prefetch for next tap
            f16x8 na[4][2];
            int nt  = (t<26)? t+1 : 0;
            int nkb = (t<26)? kb  : ((kk<3)? kb+1 : kb);
            #pragma unroll
            for (int m=0;m<4;m++)
                #pragma unroll
                for (int sp=0;sp<2;sp++)
                    na[m][sp] = *(const f16x8*)&wfrag[((((size_t)(nkb*27+nt)*4+m)*2+sp)*64 + lane)*8];
            // 3 split terms: hh, hl, lh (ll ~ 2^-22, dropped)
            #pragma unroll
            for (int dt=0;dt<2;dt++)
                #pragma unroll
                for (int m=0;m<4;m++) acc[dt][m] = __builtin_amdgcn_mfma_f32_32x32x16_f16(ca[m][0], cb[dt][0], acc[dt][m],0,0,0);
            #pragma unroll
            for (int dt=0;dt<2;dt++)
                #pragma unroll
                for (int m=0;m<4;m++) acc[dt][m] = __builtin_amdgcn_mfma_f32_32x32x16_f16(ca[m][0], cb[dt][1], acc[dt][m],0,0,0);
            #pragma unroll
            for (int dt=0;dt<2;dt++)
                #pragma unroll
                for (int m=0;m<4;m++) acc[dt][m] = __builtin_amdgcn_mfma_f32_32x32x16_f16(ca[m][1], cb[dt][0], acc[dt][m],0,0,0);
            #pragma unroll
            for (int m=0;m<4;m++)
                #pragma unroll
                for (int sp=0;sp<2;sp++) ca[m][sp] = na[m][sp];
        }
    }
    int h = H0 + wid;
    #pragma unroll
    for (int dt=0; dt<2; dt++) {
        #pragma unroll
        for (int m=0; m<4; m++) {
            #pragma unroll
            for (int reg=0; reg<16; reg++) {
                int row = (reg&3) + 8*(reg>>2) + 4*half_;
                int o = m*32 + row;
                y[((size_t)tb*CC + o)*PP + (d0+dt)*1024 + h*32 + ln] = acc[dt][m][reg];
            }
        }
    }
}

// ---------------- sum the two kb-half partials -------------------------------
__global__ __launch_bounds__(256) void conv_add(float* __restrict__ q,
                                                const float* __restrict__ p1) {
    size_t i = ((size_t)blockIdx.x*256 + threadIdx.x)*4;
    float4 a = *(const float4*)&q[i];
    float4 b = *(const float4*)&p1[i];
    a.x+=b.x; a.y+=b.y; a.z+=b.z; a.w+=b.w;
    *(float4*)&q[i] = a;
}

// ---------------- k-gemm (1x1) via f16 MFMA, 3-term split, reads xsp --------
__global__ __launch_bounds__(256) void kgemm_mfma(const half_t* __restrict__ xsp,
                                                  const half_t* __restrict__ wk,
                                                  float* __restrict__ y) {
    int tid  = threadIdx.x;
    int wid  = tid >> 6;
    int lane = tid & 63;
    int ln   = lane & 31;
    int half_ = lane >> 5;
    int hg = blockIdx.x, d = blockIdx.y, tb = blockIdx.z;
    int h = hg*4 + wid;

    f32x16 acc[4];
    #pragma unroll
    for (int m=0;m<4;m++)
        #pragma unroll
        for (int i=0;i<16;i++) acc[m][i] = 0.f;

    #pragma unroll 2
    for (int kb=0; kb<8; kb++) {
        f16x8 b[2];
        #pragma unroll
        for (int sp=0; sp<2; sp++) {
            size_t gu = (((((size_t)tb*2 + sp)*16 + (kb*2+half_))*8 + d)*34 + (h+1))*34 + (ln+1);
            b[sp] = *(const f16x8*)&xsp[gu*8];
        }
        #pragma unroll
        for (int m=0; m<4; m++) {
            const half_t* wb = wk + ((size_t)(kb*4+m))*2*64*8 + (size_t)lane*8;
            f16x8 a0 = *(const f16x8*)&wb[0*64*8];
            f16x8 a1 = *(const f16x8*)&wb[1*64*8];
            acc[m] = __builtin_amdgcn_mfma_f32_32x32x16_f16(a0, b[0], acc[m],0,0,0);
            acc[m] = __builtin_amdgcn_mfma_f32_32x32x16_f16(a0, b[1], acc[m],0,0,0);
            acc[m] = __builtin_amdgcn_mfma_f32_32x32x16_f16(a1, b[0], acc[m],0,0,0);
        }
    }
    #pragma unroll
    for (int m=0; m<4; m++) {
        #pragma unroll
        for (int reg=0; reg<16; reg++) {
            int row = (reg&3) + 8*(reg>>2) + 4*half_;
            int o = m*32 + row;
            y[((size_t)tb*CC + o)*PP + d*1024 + h*32 + ln] = acc[m][reg];
        }
    }
}

// ---------------- p-gemm via f16 MFMA: exact f16 spikes x 2-split weights ---
__global__ __launch_bounds__(256) void pgemm_mfma(const ushortT* __restrict__ spkb,
                                                  const half_t* __restrict__ wp,
                                                  float* __restrict__ y) {
    int tid  = threadIdx.x;
    int wid  = tid >> 6;
    int lane = tid & 63;
    int ln   = lane & 31;
    int half_ = lane >> 5;
    int hg = blockIdx.x, d = blockIdx.y, tb = blockIdx.z;
    int h = hg*4 + wid;
    int p = d*1024 + h*32 + ln;

    f32x16 acc[4];
    #pragma unroll
    for (int m=0;m<4;m++)
        #pragma unroll
        for (int i=0;i<16;i++) acc[m][i] = 0.f;

    #pragma unroll 2
    for (int kb=0; kb<8; kb++) {
        f16x8 b = *(const f16x8*)&spkb[(((size_t)tb*16 + (kb*2+half_))*PP + p)*8];
        #pragma unroll
        for (int m=0; m<4; m++) {
            const half_t* wb = wp + ((size_t)(kb*4+m))*2*64*8 + (size_t)lane*8;
            f16x8 a0 = *(const f16x8*)&wb[0*64*8];
            f16x8 a1 = *(const f16x8*)&wb[1*64*8];
            acc[m] = __builtin_amdgcn_mfma_f32_32x32x16_f16(a0, b, acc[m],0,0,0);
            acc[m] = __builtin_amdgcn_mfma_f32_32x32x16_f16(a1, b, acc[m],0,0,0);
        }
    }
    #pragma unroll
    for (int m=0; m<4; m++) {
        #pragma unroll
        for (int reg=0; reg<16; reg++) {
            int row = (reg&3) + 8*(reg>>2) + 4*half_;
            int o = m*32 + row;
            y[((size_t)tb*CC + o)*PP + p] = acc[m][reg];
        }
    }
}

// ---------------- per-(src,b,win,c) sum & sumsq partials ---------------------
__global__ __launch_bounds__(128) void win_stats(const float* __restrict__ q,
        const float* __restrict__ k, const float* __restrict__ x,
        float* __restrict__ rsum, float* __restrict__ rsq) {
    int blk = blockIdx.x;
    int src = blk >> 11;
    int r   = blk & 2047;
    const float* base = (src==0) ? q : ((src==1) ? k : x);
    int c  = r & 127;
    int wi = (r >> 7) & 7;
    int b  = r >> 10;
    int wd = wi>>2, wh = (wi>>1)&1, ww = wi&1;
    int tid = threadIdx.x;
    float s=0.f, s2=0.f;
    for (int t=0;t<TT;t++){
        const float* p = base + ((size_t)(t*BB+b)*CC + c)*PP;
        for (int si=tid; si<SSS; si+=128){
            int ld = si>>8, lh=(si>>4)&15, lw=si&15;
            float v = p[((wd*4+ld)<<10) + ((wh*16+lh)<<5) + (ww*16+lw)];
            s += v; s2 += v*v;
        }
    }
    __shared__ float ls[128], ls2[128];
    ls[tid]=s; ls2[tid]=s2; __syncthreads();
    for (int off=64;off>0;off>>=1){
        if(tid<off){ ls[tid]+=ls[tid+off]; ls2[tid]+=ls2[tid+off]; }
        __syncthreads();
    }
    if (tid==0){ rsum[blk]=ls[0]; rsq[blk]=ls2[0]; }
}

// ---------------- finalize per-channel stats for q,k,v ----------------------
__global__ __launch_bounds__(384) void stats_fin(const float* __restrict__ rsum,
        const float* __restrict__ rsq, float* __restrict__ sums) {
    int tid = threadIdx.x;
    int src = tid >> 7, c = tid & 127;
    float s=0.f, s2=0.f;
    for (int bw=0; bw<16; bw++){
        int idx = src*2048 + bw*128 + c;
        s  += rsum[idx];
        s2 += rsq[idx];
    }
    sums[src*256 + c]       = s;
    sums[src*256 + 128 + c] = s2;
}

// ---------------- routing: normalize regions, a_r, top-4 --------------------
__global__ __launch_bounds__(128) void route_topk(const float* __restrict__ qreg,
        const float* __restrict__ kreg,
        const float* __restrict__ qsum, const float* __restrict__ qsq,
        const float* __restrict__ ksum, const float* __restrict__ ksq,
        const float* __restrict__ qg, const float* __restrict__ qb,
        const float* __restrict__ kg, const float* __restrict__ kb,
        int* __restrict__ idxout) {
    __shared__ float qn[16*128], kn[16*128], ar[16*8];
    int tid = threadIdx.x;
    for (int e=tid; e<16*128; e+=128){
        int c = e&127;
        float qm = qsum[c]*(1.f/NPERC);
        float qv = qsq[c]*(1.f/NPERC) - qm*qm;
        float qr = rsqrtf(qv + EPSf);
        qn[e] = (qreg[e]*(1.f/(TT*SSS)) - qm)*qr*qg[c] + qb[c];
        float km = ksum[c]*(1.f/NPERC);
        float kv = ksq[c]*(1.f/NPERC) - km*km;
        float kr = rsqrtf(kv + EPSf);
        kn[e] = (kreg[e]*(1.f/(TT*SSS)) - km)*kr*kg[c] + kb[c];
    }
    __syncthreads();
    {
        int b = tid>>6, w=(tid>>3)&7, v=tid&7;
        float s=0.f;
        for (int c=0;c<128;c++) s += qn[(b*8+w)*128+c]*kn[(b*8+v)*128+c];
        ar[(b*8+w)*8+v] = s * 0.25f;
    }
    __syncthreads();
    if (tid < 16){
        const float* row = &ar[tid*8];
        bool used[8] = {false,false,false,false,false,false,false,false};
        for (int j=0;j<4;j++){
            int best=0; float bv=-3.0e38f;
            for (int v=0; v<8; v++){
                if (!used[v] && row[v] > bv){ bv=row[v]; best=v; }
            }
            used[best]=true;
            idxout[tid*4+j]=best;
        }
    }
}

// ---------------- LIF+BN for q,k,v in ONE launch (grid.y = src) -------------
__global__ __launch_bounds__(256) void lif_bn_win3(const float* __restrict__ qin,
        const float* __restrict__ kin, const float* __restrict__ xin,
        float* __restrict__ qs, float* __restrict__ ks, float* __restrict__ vs,
        const float* __restrict__ stats,
        const float* __restrict__ qg, const float* __restrict__ qb,
        const float* __restrict__ kg, const float* __restrict__ kb,
        const float* __restrict__ vg, const float* __restrict__ vb) {
    int src = blockIdx.y;
    const float* in  = (src==0) ? qin : ((src==1) ? kin : xin);
    float*       spk = (src==0) ? qs  : ((src==1) ? ks  : vs);
    const float* gamma = (src==0) ? qg : ((src==1) ? kg : vg);
    const float* beta  = (src==0) ? qb : ((src==1) ? kb : vb);
    int e = blockIdx.x*256 + threadIdx.x;
    if (e >= BB*CC*PP) return;
    int p = e & (PP-1);
    int c = (e >> 13) & 127;
    int b = e >> 20;
    float mean = stats[src*256 + c]*(1.f/NPERC);
    float var  = stats[src*256 + 128 + c]*(1.f/NPERC) - mean*mean;
    float sc = rsqrtf(var+EPSf)*gamma[c];
    float sh = beta[c] - mean*sc;
    int d = p>>10, h=(p>>5)&31, w=p&31;
    int wi = ((d>>2)*2 + (h>>4))*2 + (w>>4);
    int si = (((d&3)<<4) + (h&15))*16 + (w&15);
    size_t widx = ((size_t)(b*NWIN+wi)*CC + c)*SSS + si;
    float v=0.f;
    #pragma unroll
    for (int t=0;t<TT;t++){
        float xn = in[(size_t)t*TSTRIDE + e]*sc + sh;
        v = (v+xn)*0.5f;
        float s = (v>=VTH)?1.f:0.f;
        spk[(size_t)t*TSTRIDE + widx] = s;
        v *= (1.f - s);
    }
}

// ---------------- window attention + output LIF -> f16 spike frags ----------
// spkb[tb = t*B+b][icg16][p8192][8] f16 {0,1}
__global__ __launch_bounds__(256) void attn_lif(const float* __restrict__ qspk,
        const float* __restrict__ kspk, const float* __restrict__ vspk,
        const int* __restrict__ idx, ushortT* __restrict__ spkb) {
    int id = blockIdx.x*256 + threadIdx.x;   // B*W*H*S = 131072
    if (id >= BB*NWIN*NHEAD*SSS) return;
    int s  = id & 1023;
    int hh = (id>>10) & 7;
    int wi = (id>>13) & 7;
    int b  = id>>16;
    int bw = b*NWIN+wi;
    size_t qbase = ((size_t)bw*CC + hh*HDIM)*SSS + s;
    size_t sbase[4];
    #pragma unroll
    for (int j=0;j<4;j++){
        int src = idx[bw*4+j];
        sbase[j] = ((size_t)(b*NWIN+src)*CC + hh*HDIM)*SSS + s;
    }
    int wd = wi>>2, wh = (wi>>1)&1, ww = wi&1;
    int d3 = wd*4 + (s>>8), h3 = wh*16 + ((s>>4)&15), w3 = ww*16 + (s&15);
    int p  = (d3<<10) + (h3<<5) + w3;

    float v=0.f;
    float v2[16];
    #pragma unroll
    for (int dd=0; dd<16; dd++) v2[dd]=0.f;

    #pragma unroll 1
    for (int t=0;t<TT;t++){
        size_t toff = (size_t)t*TSTRIDE;
        float km[16], vm[16];
        #pragma unroll
        for (int dd=0;dd<16;dd++){ km[dd]=0.f; vm[dd]=0.f; }
        #pragma unroll
        for (int j=0;j<4;j++){
            const float* kp = kspk+toff+sbase[j];
            const float* vp = vspk+toff+sbase[j];
            #pragma unroll
            for (int dd=0; dd<16; dd++){
                km[dd] += kp[(size_t)dd*SSS];
                vm[dd] += vp[(size_t)dd*SSS];
            }
        }
        const float* qp = qspk+toff+qbase;
        float att=0.f;
        #pragma unroll
        for (int dd=0;dd<16;dd++) att += qp[(size_t)dd*SSS]*km[dd];
        att *= 0.25f;
        v = (v+att)*0.5f;
        float sp = (v>=VTH)?1.f:0.f;
        v *= (1.f-sp);
        float spq = sp*0.25f;
        union { ushortT u[8]; uint4 q4; } pk0, pk1;
        #pragma unroll
        for (int dd=0;dd<16;dd++){
            float ov = spq*vm[dd];
            v2[dd] = (v2[dd]+ov)*0.5f;
            float s2 = (v2[dd]>=VTH)?1.f:0.f;
            v2[dd] *= (1.f-s2);
            ushortT bs = (s2 != 0.f) ? (ushortT)0x3C00 : (ushortT)0;   // f16 1.0
            if (dd < 8) pk0.u[dd] = bs; else pk1.u[dd-8] = bs;
        }
        int tb2 = t*BB + b;
        size_t base = (((size_t)tb2*16 + hh*2)*PP + p)*8;
        *(uint4*)&spkb[base] = pk0.q4;
        *(uint4*)&spkb[base + (size_t)PP*8] = pk1.q4;
    }
}

// ---------------- p-stats: partials over (tb,c), then finalize ---------------
__global__ __launch_bounds__(256) void pstats_part(const float* __restrict__ xin,
        float* __restrict__ part_sum, float* __restrict__ part_sq) {
    int blk = blockIdx.x;                    // tb*128 + c
    int c = blk & 127, tb = blk >> 7;
    int tid = threadIdx.x;
    const float* p = xin + ((size_t)tb*CC + c)*PP;
    float s=0.f, s2=0.f;
    for (int i=tid; i<PP; i+=256){ float v=p[i]; s+=v; s2+=v*v; }
    __shared__ float ls[256], ls2[256];
    ls[tid]=s; ls2[tid]=s2; __syncthreads();
    for (int off=128; off>0; off>>=1){
        if (tid<off){ ls[tid]+=ls[tid+off]; ls2[tid]+=ls2[tid+off]; }
        __syncthreads();
    }
    if (tid==0){ part_sum[blk]=ls[0]; part_sq[blk]=ls2[0]; }
}

__global__ __launch_bounds__(128) void pstats_fin(const float* __restrict__ part_sum,
        const float* __restrict__ part_sq, float* __restrict__ sum,
        float* __restrict__ sq) {
    int c = threadIdx.x;
    float s=0.f, s2=0.f;
    for (int tb=0; tb<8; tb++){
        s  += part_sum[tb*128+c];
        s2 += part_sq[tb*128+c];
    }
    sum[c]=s; sq[c]=s2;
}

// ---------------- final BN apply ---------------------------------------------
__global__ __launch_bounds__(256) void bn_apply(const float* __restrict__ xin,
        float* __restrict__ yout,
        const float* __restrict__ sum, const float* __restrict__ sq,
        const float* __restrict__ gamma, const float* __restrict__ beta) {
    size_t i = (size_t)blockIdx.x*256 + threadIdx.x;
    if (i >= (size_t)TT*BB*CC*PP) return;
    int c = (int)((i>>13)&127);
    float mean = sum[c]*(1.f/NPERC);
    float var  = sq[c]*(1.f/NPERC) - mean*mean;
    float sc = rsqrtf(var+EPSf)*gamma[c];
    float sh = beta[c] - mean*sc;
    yout[i] = xin[i]*sc + sh;
}

extern "C" void kernel_launch(void* const* d_in, const int* in_sizes, int n_in,
                              void* d_out, int out_size, void* d_ws, size_t ws_size,
                              hipStream_t stream) {
    const float* x  = (const float*)d_in[0];
    const float* qw = (const float*)d_in[1];
    const float* qg = (const float*)d_in[2];
    const float* qb = (const float*)d_in[3];
    const float* kw = (const float*)d_in[4];
    const float* kg = (const float*)d_in[5];
    const float* kb = (const float*)d_in[6];
    const float* vg = (const float*)d_in[7];
    const float* vb = (const float*)d_in[8];
    const float* pw = (const float*)d_in[9];
    const float* pg = (const float*)d_in[10];
    const float* pb = (const float*)d_in[11];
    float* out = (float*)d_out;
    float* ws  = (float*)d_ws;

    const size_t NEL = (size_t)TT*TSTRIDE;   // 8,388,608 floats
    float* qconv = ws;                       // conv part0
    float* kconv = ws + NEL;                 // conv part1, then kconv
    float* qspk  = ws + 2*NEL;
    float* kspk  = ws + 3*NEL;
    float* vspk  = ws + 4*NEL;
    float* wmodT = ws + 5*NEL;               // 442368 floats
    float* stats = ws + 5*NEL + 442368;
    float *qsum=stats,     *qsq=stats+128,  *ksum=stats+256, *ksq=stats+384,
          *psum=stats+768, *psq=stats+896;
    float* rsum = stats + 1024;              // 6144
    float* rsq  = rsum + 6144;               // 6144
    float* ppart_sum = rsq + 6144;           // 1024
    float* ppart_sq  = ppart_sum + 1024;     // 1024
    int*   idxp = (int*)(ppart_sq + 1024);   // 64 ints

    // lifetimes (S9 layout):
    //  xsp f16 (37.8MB) at 2NEL (spans into kspk region) until kgemm done
    //  wfrag/wkfrag f16 at 4NEL; dead before lif writes vspk
    //  conv part1 at NEL; conv_add consumes it BEFORE kgemm rewrites (kconv)
    //  float spikes q/k/v at 2NEL/3NEL/4NEL (xsp dead by then)
    //  spkb f16 at NEL (kconv dead after lif)
    //  wpfrag at 4NEL after attn (vspk dead); pconv at 2NEL (qspk dead)
    half_t* xsp    = (half_t*)(ws + 2*NEL);
    half_t* wfrag  = (half_t*)(ws + 4*NEL);
    half_t* wkfrag = (half_t*)(ws + 4*NEL) + 884736;
    half_t* wpfrag = (half_t*)(ws + 4*NEL);
    ushortT* spkb  = (ushortT*)(ws + NEL);
    float*   pconv = ws + 2*NEL;
    float*   part1 = kconv;

    prep_wmodT<<<64,256,0,stream>>>(qw, wmodT);
    prep_wfrag<<<216,256,0,stream>>>(wmodT, wfrag);
    prep_w1frag<<<8,256,0,stream>>>(kw, wkfrag);
    build_xsplit<<<4624,256,0,stream>>>(x, xsp);
    {
        dim3 cg(8,4,16);
        conv_mfma2<<<cg,256,0,stream>>>(xsp, wfrag, qconv, part1);
    }
    conv_add<<<8192,256,0,stream>>>(qconv, part1);
    {
        dim3 gg(8,8,8);
        kgemm_mfma<<<gg,256,0,stream>>>(xsp, wkfrag, kconv);
    }
    win_stats<<<6144,128,0,stream>>>(qconv, kconv, x, rsum, rsq);
    stats_fin<<<1,384,0,stream>>>(rsum, rsq, stats);
    route_topk<<<1,128,0,stream>>>(rsum, rsum+2048, qsum,qsq,ksum,ksq,qg,qb,kg,kb,idxp);
    {
        dim3 lg(8192,3);
        lif_bn_win3<<<lg,256,0,stream>>>(qconv,kconv,x, qspk,kspk,vspk,
                                         stats, qg,qb,kg,kb,vg,vb);
    }
    attn_lif<<<512,256,0,stream>>>(qspk,kspk,vspk,idxp,spkb);
    prep_w1frag<<<8,256,0,stream>>>(pw, wpfrag);
    {
        dim3 gg(8,8,8);
        pgemm_mfma<<<gg,256,0,stream>>>(spkb, wpfrag, pconv);
    }
    pstats_part<<<1024,256,0,stream>>>(pconv, ppart_sum, ppart_sq);
    pstats_fin<<<1,128,0,stream>>>(ppart_sum, ppart_sq, psum, psq);
    bn_apply<<<32768,256,0,stream>>>(pconv, out, psum, psq, pg, pb);
}